// Round 2
// baseline (234.566 us; speedup 1.0000x reference)
//
#include <hip/hip_runtime.h>
#include <hip/hip_bf16.h>

// Problem constants (GraphConv: B=4, C=64, N=16384, K=32)
#define BB 4
#define CC 64
#define NN 16384
#define KK 32
#define PTS (BB * NN)   // 65536 points
#define NB3 512         // total partial slots for gather kernel (128 points each)

// ---------------------------------------------------------------------------
// k1: z = W @ x computed per 64-point chunk per wave; lane = point.
//     x[b][c][n] read coalesced (64 dword loads, stride N); W[o][c] is
//     wave-uniform -> scalar loads. Result transposed through LDS so the
//     store zt[b'][n][o] is coalesced (256 B per wave instr).
//     ZB = number of batches held in zt (4 = full path, 1 = per-batch path).
// ---------------------------------------------------------------------------
template <int ZB>
__global__ __launch_bounds__(256) void k1_wx_t(const float* __restrict__ x,
                                               const float* __restrict__ W,
                                               float* __restrict__ zt,
                                               int b0) {
    __shared__ float tile[4][64 * 65];  // per-wave 64x64 tile, pad 65 (2-way banks = free)
    const int tid  = threadIdx.x;
    const int lane = tid & 63;
    const int w    = tid >> 6;
    const int chunk = blockIdx.x * 4 + w;       // ZB*256 chunks total
    const int bl = chunk >> 8;                  // local batch 0..ZB-1
    const int b  = b0 + bl;                     // global batch
    const int n0 = (chunk & 255) << 6;

    const float* xb = x + (size_t)b * CC * NN + n0 + lane;
    float xr[64];
#pragma unroll
    for (int c = 0; c < 64; ++c) xr[c] = xb[(size_t)c * NN];

    float* tw = tile[w];
#pragma unroll 4
    for (int o = 0; o < 64; ++o) {
        const float* wrow = W + (o << 6);       // uniform address -> s_load
        float a0 = 0.f, a1 = 0.f, a2 = 0.f, a3 = 0.f;
#pragma unroll
        for (int c = 0; c < 64; c += 4) {
            a0 = fmaf(wrow[c + 0], xr[c + 0], a0);
            a1 = fmaf(wrow[c + 1], xr[c + 1], a1);
            a2 = fmaf(wrow[c + 2], xr[c + 2], a2);
            a3 = fmaf(wrow[c + 3], xr[c + 3], a3);
        }
        tw[o * 65 + lane] = (a0 + a1) + (a2 + a3);   // banks (o+lane)%32: 2-way, free
    }
    __syncthreads();
    float* ztb = zt + ((size_t)bl * NN + n0) * CC + lane;
#pragma unroll 4
    for (int j = 0; j < 64; ++j) {
        ztb[(size_t)j * CC] = tw[lane * 65 + j];     // coalesced 256 B store per row
    }
}

// ---------------------------------------------------------------------------
// k3: h[b][o][n] = mean_k zt[b][ e[b,n,k] ][o]; lane = channel o.
//     Edge indices are int32 (harness converts all integer inputs to int32!).
//     One coalesced 32-lane index load, broadcast via v_readlane (SGPR) ->
//     gather base is scalar, gather reads are coalesced 256 B rows from an
//     L2-resident zt slice (4 MB / batch). Also accumulates per-channel
//     sum / sumsq partials for BN, and writes raw h transposed (via LDS)
//     into d_out, coalesced.
// ---------------------------------------------------------------------------
template <int ZB>
__global__ __launch_bounds__(256) void k3_gather(const float* __restrict__ zt,
                                                 const int* __restrict__ edges,
                                                 float* __restrict__ hout,
                                                 float* __restrict__ p1,
                                                 float* __restrict__ p2,
                                                 int b0) {
    __shared__ float otile[64 * 65];
    __shared__ float red[4][64];
    const int tid  = threadIdx.x;
    const int lane = tid & 63;
    const int w    = tid >> 6;
    float s1 = 0.f, s2 = 0.f;

    for (int t = 0; t < 2; ++t) {
        const int tlocal = blockIdx.x * 128 + t * 64;    // local 64-point tile
        const int bl = tlocal >> 14;                     // N = 2^14
        const int b  = b0 + bl;
        const int n0 = tlocal & (NN - 1);
        const float* ztb = zt + (size_t)bl * NN * CC + lane;

#pragma unroll
        for (int i = 0; i < 16; ++i) {
            const int j = w * 16 + i;
            const int p = b * NN + n0 + j;               // global point
            const int* ep = edges + (size_t)p * KK;      // int32 indices
            const int mye = ep[lane & 31];               // lanes 32..63 duplicate 0..31
            float a0 = 0.f, a1 = 0.f, a2 = 0.f, a3 = 0.f;
#pragma unroll
            for (int k = 0; k < KK; k += 4) {
                const int e0 = __builtin_amdgcn_readlane(mye, k + 0);
                const int e1 = __builtin_amdgcn_readlane(mye, k + 1);
                const int e2 = __builtin_amdgcn_readlane(mye, k + 2);
                const int e3 = __builtin_amdgcn_readlane(mye, k + 3);
                a0 += ztb[(size_t)e0 * CC];
                a1 += ztb[(size_t)e1 * CC];
                a2 += ztb[(size_t)e2 * CC];
                a3 += ztb[(size_t)e3 * CC];
            }
            const float h = ((a0 + a1) + (a2 + a3)) * (1.0f / KK);
            s1 += h;
            s2 += h * h;
            otile[lane * 65 + j] = h;                    // banks (lane+j)%32: 2-way, free
        }
        __syncthreads();
        const size_t obase = (size_t)b * CC * NN + n0 + lane;
#pragma unroll
        for (int r = 0; r < 16; ++r) {
            const int o = w * 16 + r;
            hout[obase + (size_t)o * NN] = otile[o * 65 + lane];  // coalesced 256 B
        }
        __syncthreads();
    }

    // block-level channel reduction of BN partials; slot = global block id
    const int pslot = b0 * 128 + blockIdx.x;
    red[w][lane] = s1;
    __syncthreads();
    if (w == 0)
        p1[pslot * 64 + lane] = red[0][lane] + red[1][lane] + red[2][lane] + red[3][lane];
    __syncthreads();
    red[w][lane] = s2;
    __syncthreads();
    if (w == 0)
        p2[pslot * 64 + lane] = red[0][lane] + red[1][lane] + red[2][lane] + red[3][lane];
}

// ---------------------------------------------------------------------------
// k4: reduce NB3 partials per channel -> scale/shift (biased var, eps=1e-5).
// ---------------------------------------------------------------------------
__global__ __launch_bounds__(256) void k4_stats(const float* __restrict__ p1,
                                                const float* __restrict__ p2,
                                                const float* __restrict__ gamma,
                                                const float* __restrict__ beta,
                                                float* __restrict__ sc,
                                                float* __restrict__ sh) {
    __shared__ float r1[256], r2[256];
    const int tid = threadIdx.x;
    float s1 = 0.f, s2 = 0.f;
    for (int i = tid; i < NB3 * 64; i += 256) {  // channel = i & 63 is constant per thread
        s1 += p1[i];
        s2 += p2[i];
    }
    r1[tid] = s1;
    r2[tid] = s2;
    __syncthreads();
    if (tid < 64) {
        const float t1 = r1[tid] + r1[tid + 64] + r1[tid + 128] + r1[tid + 192];
        const float t2 = r2[tid] + r2[tid + 64] + r2[tid + 128] + r2[tid + 192];
        const float inv = 1.0f / (float)PTS;
        const float mu  = t1 * inv;
        const float var = t2 * inv - mu * mu;     // biased variance (torch BN)
        const float s   = gamma[tid] * rsqrtf(var + 1e-5f);
        sc[tid] = s;
        sh[tid] = beta[tid] - mu * s;
    }
}

// ---------------------------------------------------------------------------
// k5: in-place BN apply + LeakyReLU(0.2) on d_out, float4 vectorized.
// ---------------------------------------------------------------------------
__global__ __launch_bounds__(256) void k5_bn(float* __restrict__ out,
                                             const float* __restrict__ sc,
                                             const float* __restrict__ sh) {
    const int total4 = BB * CC * NN / 4;          // 1,048,576 float4
    for (int i = blockIdx.x * 256 + threadIdx.x; i < total4; i += gridDim.x * 256) {
        const int c = (i >> 12) & 63;             // N/4 = 4096 float4 per channel row
        const float s = sc[c];
        const float t = sh[c];
        float4 v = ((const float4*)out)[i];
        float y;
        y = fmaf(v.x, s, t); v.x = y > 0.f ? y : 0.2f * y;
        y = fmaf(v.y, s, t); v.y = y > 0.f ? y : 0.2f * y;
        y = fmaf(v.z, s, t); v.z = y > 0.f ? y : 0.2f * y;
        y = fmaf(v.w, s, t); v.w = y > 0.f ? y : 0.2f * y;
        ((float4*)out)[i] = v;
    }
}

extern "C" void kernel_launch(void* const* d_in, const int* in_sizes, int n_in,
                              void* d_out, int out_size, void* d_ws, size_t ws_size,
                              hipStream_t stream) {
    const float* x     = (const float*)d_in[0];
    const int*   edges = (const int*)d_in[1];      // harness: integer inputs are int32
    const float* W     = (const float*)d_in[2];
    const float* gamma = (const float*)d_in[3];
    const float* beta  = (const float*)d_in[4];
    float* out = (float*)d_out;
    float* ws  = (float*)d_ws;

    const size_t zt1   = (size_t)NN * CC;                 // one batch of zt (1 M floats)
    const size_t parts = (size_t)NB3 * CC * 2 + 128;      // p1 + p2 + sc + sh
    const size_t need_full  = (zt1 * BB + parts) * sizeof(float);  // ~16.6 MB
    const bool   full = (ws_size >= need_full);

    const size_t zt_floats = full ? zt1 * BB : zt1;
    float* zt = ws;
    float* p1 = ws + zt_floats;
    float* p2 = p1 + (size_t)NB3 * CC;
    float* sc = p2 + (size_t)NB3 * CC;
    float* sh = sc + CC;

    if (full) {
        hipLaunchKernelGGL((k1_wx_t<BB>),   dim3(BB * 64),  dim3(256), 0, stream, x, W, zt, 0);
        hipLaunchKernelGGL((k3_gather<BB>), dim3(BB * 128), dim3(256), 0, stream,
                           zt, edges, out, p1, p2, 0);
    } else {
        for (int b = 0; b < BB; ++b) {
            hipLaunchKernelGGL((k1_wx_t<1>),   dim3(64),  dim3(256), 0, stream, x, W, zt, b);
            hipLaunchKernelGGL((k3_gather<1>), dim3(128), dim3(256), 0, stream,
                               zt, edges, out, p1, p2, b);
        }
    }
    hipLaunchKernelGGL(k4_stats, dim3(1), dim3(256), 0, stream, p1, p2, gamma, beta, sc, sh);
    hipLaunchKernelGGL(k5_bn, dim3(2048), dim3(256), 0, stream, out, sc, sh);
}

// Round 4
// 208.001 us; speedup vs baseline: 1.1277x; 1.1277x over previous
//
#include <hip/hip_runtime.h>
#include <hip/hip_bf16.h>

// Problem constants (GraphConv: B=4, C=64, N=16384, K=32)
#define BB 4
#define CC 64
#define NN 16384
#define KK 32
#define PTS (BB * NN)   // 65536 points
#define NB3 512         // total partial slots for gather kernel (128 points each)

// ---------------------------------------------------------------------------
// k1 (v2): zt[b][n][o] = sum_c W[o][c] * x[b][c][n], 64-point chunk per block.
//   Phase 1: stage x[b][0:64][n0:n0+64] into LDS (16 coalesced 256B rows/wave).
//   Phase 2: wave w computes o in [16w,16w+16); lane = point. x from LDS
//            (2-way reads = free), W wave-uniform -> s_load, 1024 FMA/lane.
//   Phase 3: transpose through zs so the global store is 1KB/instr coalesced.
//   Per-batch grid = 256 blocks (all CUs), LDS = 33 KB.
// ---------------------------------------------------------------------------
template <int ZB>
__global__ __launch_bounds__(256) void k1_wx_t(const float* __restrict__ x,
                                               const float* __restrict__ W,
                                               float* __restrict__ zt,
                                               int b0) {
    __shared__ float xs[64 * 65];
    __shared__ float zs[64 * 65];
    const int tid  = threadIdx.x;
    const int lane = tid & 63;
    const int w    = tid >> 6;
    const int chunk = blockIdx.x;               // ZB*256 chunks, 64 points each
    const int bl = chunk >> 8;                  // local batch
    const int b  = b0 + bl;                     // global batch
    const int n0 = (chunk & 255) << 6;

    // Phase 1: stage x chunk. iter i: waves load rows c = 4i+w (coalesced).
    const float* xb = x + (size_t)b * CC * NN + n0;
#pragma unroll
    for (int i = 0; i < 16; ++i) {
        const int c = i * 4 + w;
        xs[c * 65 + lane] = xb[(size_t)c * NN + lane];
    }
    __syncthreads();

    // Phase 2: per-lane x column into regs (64 ds_read, 2-way = free).
    float xr[64];
#pragma unroll
    for (int c = 0; c < 64; ++c) xr[c] = xs[c * 65 + lane];

    float acc[16];
#pragma unroll
    for (int i = 0; i < 16; ++i) {
        const int o = w * 16 + i;
        const float* wrow = W + (o << 6);       // uniform -> scalar loads
        float a0 = 0.f, a1 = 0.f, a2 = 0.f, a3 = 0.f;
#pragma unroll
        for (int c = 0; c < 64; c += 4) {
            a0 = fmaf(wrow[c + 0], xr[c + 0], a0);
            a1 = fmaf(wrow[c + 1], xr[c + 1], a1);
            a2 = fmaf(wrow[c + 2], xr[c + 2], a2);
            a3 = fmaf(wrow[c + 3], xr[c + 3], a3);
        }
        acc[i] = (a0 + a1) + (a2 + a3);
    }

    // Phase 3: transpose (lane=point holds 16 o's -> zs[point][o]).
#pragma unroll
    for (int i = 0; i < 16; ++i) zs[lane * 65 + w * 16 + i] = acc[i];
    __syncthreads();

    float* zo = zt + ((size_t)bl * NN + n0) * CC;
#pragma unroll
    for (int i = 0; i < 16; ++i) {
        const int r = i * 4 + w;                // block writes 4 rows = 1KB/iter
        zo[r * CC + lane] = zs[r * 65 + lane];
    }
}

// ---------------------------------------------------------------------------
// k3: h[b][o][n] = mean_k zt[b][ e[b,n,k] ][o]; lane = channel o.
//     Edge indices are int32 (harness converts integer inputs to int32).
//     One coalesced 32-lane index load, broadcast via readlane -> gather
//     reads are coalesced 256 B rows from the L2-resident zt slice
//     (4 MB / batch). Accumulates per-channel sum/sumsq partials for BN and
//     writes raw h transposed (via LDS) into d_out, coalesced.
// ---------------------------------------------------------------------------
template <int ZB>
__global__ __launch_bounds__(256) void k3_gather(const float* __restrict__ zt,
                                                 const int* __restrict__ edges,
                                                 float* __restrict__ hout,
                                                 float* __restrict__ p1,
                                                 float* __restrict__ p2,
                                                 int b0) {
    __shared__ float otile[64 * 65];
    __shared__ float red[4][64];
    const int tid  = threadIdx.x;
    const int lane = tid & 63;
    const int w    = tid >> 6;
    float s1 = 0.f, s2 = 0.f;

    for (int t = 0; t < 2; ++t) {
        const int tlocal = blockIdx.x * 128 + t * 64;    // local 64-point tile
        const int bl = tlocal >> 14;                     // N = 2^14
        const int b  = b0 + bl;
        const int n0 = tlocal & (NN - 1);
        const float* ztb = zt + (size_t)bl * NN * CC + lane;

#pragma unroll
        for (int i = 0; i < 16; ++i) {
            const int j = w * 16 + i;
            const int p = b * NN + n0 + j;               // global point
            const int* ep = edges + (size_t)p * KK;      // int32 indices
            const int mye = ep[lane & 31];               // lanes 32..63 dup 0..31
            float a0 = 0.f, a1 = 0.f, a2 = 0.f, a3 = 0.f;
#pragma unroll
            for (int k = 0; k < KK; k += 4) {
                const int e0 = __builtin_amdgcn_readlane(mye, k + 0);
                const int e1 = __builtin_amdgcn_readlane(mye, k + 1);
                const int e2 = __builtin_amdgcn_readlane(mye, k + 2);
                const int e3 = __builtin_amdgcn_readlane(mye, k + 3);
                a0 += ztb[(size_t)e0 * CC];
                a1 += ztb[(size_t)e1 * CC];
                a2 += ztb[(size_t)e2 * CC];
                a3 += ztb[(size_t)e3 * CC];
            }
            const float h = ((a0 + a1) + (a2 + a3)) * (1.0f / KK);
            s1 += h;
            s2 += h * h;
            otile[lane * 65 + j] = h;                    // 2-way banks = free
        }
        __syncthreads();
        const size_t obase = (size_t)b * CC * NN + n0 + lane;
#pragma unroll
        for (int r = 0; r < 16; ++r) {
            const int o = w * 16 + r;
            hout[obase + (size_t)o * NN] = otile[o * 65 + lane];  // coalesced
        }
        __syncthreads();
    }

    // block-level channel reduction of BN partials; slot = global block id
    const int pslot = b0 * 128 + blockIdx.x;
    red[w][lane] = s1;
    __syncthreads();
    if (w == 0)
        p1[pslot * 64 + lane] = red[0][lane] + red[1][lane] + red[2][lane] + red[3][lane];
    __syncthreads();
    red[w][lane] = s2;
    __syncthreads();
    if (w == 0)
        p2[pslot * 64 + lane] = red[0][lane] + red[1][lane] + red[2][lane] + red[3][lane];
}

// ---------------------------------------------------------------------------
// k4: reduce NB3 partials per channel -> scale/shift (biased var, eps=1e-5).
// ---------------------------------------------------------------------------
__global__ __launch_bounds__(256) void k4_stats(const float* __restrict__ p1,
                                                const float* __restrict__ p2,
                                                const float* __restrict__ gamma,
                                                const float* __restrict__ beta,
                                                float* __restrict__ sc,
                                                float* __restrict__ sh) {
    __shared__ float r1[256], r2[256];
    const int tid = threadIdx.x;
    float s1 = 0.f, s2 = 0.f;
    for (int i = tid; i < NB3 * 64; i += 256) {  // channel = i & 63 constant/thread
        s1 += p1[i];
        s2 += p2[i];
    }
    r1[tid] = s1;
    r2[tid] = s2;
    __syncthreads();
    if (tid < 64) {
        const float t1 = r1[tid] + r1[tid + 64] + r1[tid + 128] + r1[tid + 192];
        const float t2 = r2[tid] + r2[tid + 64] + r2[tid + 128] + r2[tid + 192];
        const float inv = 1.0f / (float)PTS;
        const float mu  = t1 * inv;
        const float var = t2 * inv - mu * mu;     // biased variance (torch BN)
        const float s   = gamma[tid] * rsqrtf(var + 1e-5f);
        sc[tid] = s;
        sh[tid] = beta[tid] - mu * s;
    }
}

// ---------------------------------------------------------------------------
// k5: in-place BN apply + LeakyReLU(0.2) on d_out, float4 vectorized.
// ---------------------------------------------------------------------------
__global__ __launch_bounds__(256) void k5_bn(float* __restrict__ out,
                                             const float* __restrict__ sc,
                                             const float* __restrict__ sh) {
    const int total4 = BB * CC * NN / 4;          // 1,048,576 float4
    for (int i = blockIdx.x * 256 + threadIdx.x; i < total4; i += gridDim.x * 256) {
        const int c = (i >> 12) & 63;             // N/4 = 4096 float4 per channel
        const float s = sc[c];
        const float t = sh[c];
        float4 v = ((const float4*)out)[i];
        float y;
        y = fmaf(v.x, s, t); v.x = y > 0.f ? y : 0.2f * y;
        y = fmaf(v.y, s, t); v.y = y > 0.f ? y : 0.2f * y;
        y = fmaf(v.z, s, t); v.z = y > 0.f ? y : 0.2f * y;
        y = fmaf(v.w, s, t); v.w = y > 0.f ? y : 0.2f * y;
        ((float4*)out)[i] = v;
    }
}

extern "C" void kernel_launch(void* const* d_in, const int* in_sizes, int n_in,
                              void* d_out, int out_size, void* d_ws, size_t ws_size,
                              hipStream_t stream) {
    const float* x     = (const float*)d_in[0];
    const int*   edges = (const int*)d_in[1];      // integer inputs are int32
    const float* W     = (const float*)d_in[2];
    const float* gamma = (const float*)d_in[3];
    const float* beta  = (const float*)d_in[4];
    float* out = (float*)d_out;
    float* ws  = (float*)d_ws;

    const size_t zt1   = (size_t)NN * CC;                 // one batch of zt
    const size_t parts = (size_t)NB3 * CC * 2 + 128;      // p1 + p2 + sc + sh
    const size_t need_full = (zt1 * BB + parts) * sizeof(float);  // ~17.0 MB
    const bool   full = (ws_size >= need_full);

    const size_t zt_floats = full ? zt1 * BB : zt1;
    float* zt = ws;
    float* p1 = ws + zt_floats;
    float* p2 = p1 + (size_t)NB3 * CC;
    float* sc = p2 + (size_t)NB3 * CC;
    float* sh = sc + CC;

    if (full) {
        hipLaunchKernelGGL((k1_wx_t<BB>),   dim3(BB * 256), dim3(256), 0, stream, x, W, zt, 0);
        hipLaunchKernelGGL((k3_gather<BB>), dim3(BB * 128), dim3(256), 0, stream,
                           zt, edges, out, p1, p2, 0);
    } else {
        for (int b = 0; b < BB; ++b) {
            hipLaunchKernelGGL((k1_wx_t<1>),   dim3(256), dim3(256), 0, stream, x, W, zt, b);
            hipLaunchKernelGGL((k3_gather<1>), dim3(128), dim3(256), 0, stream,
                               zt, edges, out, p1, p2, b);
        }
    }
    hipLaunchKernelGGL(k4_stats, dim3(1), dim3(256), 0, stream, p1, p2, gamma, beta, sc, sh);
    hipLaunchKernelGGL(k5_bn, dim3(2048), dim3(256), 0, stream, out, sc, sh);
}